// Round 1
// baseline (187.728 us; speedup 1.0000x reference)
//
#include <hip/hip_runtime.h>
#include <cstdint>
#include <cstddef>

#define NN 4096
#define FDIM 256

typedef __attribute__((ext_vector_type(4))) float fx4;
typedef __attribute__((ext_vector_type(8))) short s8v;

__device__ inline uint16_t f2bf(float f) {
    union { float f; uint32_t u; } v; v.f = f;
    uint32_t u = v.u;
    uint32_t r = (u + 0x7FFFu + ((u >> 16) & 1u)) >> 16;
    return (uint16_t)r;
}

// ---------------- h = x @ W.T + b  (fp32, 64x64 tiles, 4x4 micro) ----------------
__global__ __launch_bounds__(256) void k_h(const float* __restrict__ x,
        const float* __restrict__ W, const float* __restrict__ bias,
        float* __restrict__ h) {
    __shared__ __align__(16) float xs[64 * 68];  // [k][i] swizzled
    __shared__ __align__(16) float wt[64 * 68];  // [k][f] swizzled
    const int bi = blockIdx.x, bf = blockIdx.y;
    const int t = threadIdx.x;
    const int tx = t & 15, ty = t >> 4;
    float acc[4][4] = {};
    for (int k0 = 0; k0 < 256; k0 += 64) {
        for (int e = t; e < 4096; e += 256) {
            const int r = e >> 6, c = e & 63;
            const int sw = 8 * ((c & 7) ^ ((c >> 3) & 7));
            xs[c * 68 + (r ^ sw)] = x[(size_t)(bi * 64 + r) * 256 + k0 + c];
            wt[c * 68 + (r ^ sw)] = W[(size_t)(bf * 64 + r) * 256 + k0 + c];
        }
        __syncthreads();
        #pragma unroll 8
        for (int k = 0; k < 64; ++k) {
            const int sw = 8 * ((k & 7) ^ ((k >> 3) & 7));
            const fx4 av = *(const fx4*)(xs + k * 68 + ((ty * 4) ^ sw));
            const fx4 bv = *(const fx4*)(wt + k * 68 + ((tx * 4) ^ sw));
            #pragma unroll
            for (int u = 0; u < 4; ++u)
                #pragma unroll
                for (int v = 0; v < 4; ++v)
                    acc[u][v] += av[u] * bv[v];
        }
        __syncthreads();
    }
    #pragma unroll
    for (int u = 0; u < 4; ++u)
        #pragma unroll
        for (int v = 0; v < 4; ++v) {
            const int i = bi * 64 + ty * 4 + u;
            const int f = bf * 64 + tx * 4 + v;
            h[(size_t)i * 256 + f] = acc[u][v] + bias[f];
        }
}

// ---------------- a1 = h @ w1, a2 = h @ w2 ----------------
__global__ __launch_bounds__(256) void k_a(const float* __restrict__ h,
        const float* __restrict__ att_w, float* __restrict__ a1,
        float* __restrict__ a2) {
    const int wv = threadIdx.x >> 6, l = threadIdx.x & 63;
    const int i = blockIdx.x * 4 + wv;
    float s1 = 0.f, s2 = 0.f;
    #pragma unroll
    for (int c = l; c < 256; c += 64) {
        const float hv = h[(size_t)i * 256 + c];
        s1 += hv * att_w[c];
        s2 += hv * att_w[256 + c];
    }
    #pragma unroll
    for (int d = 32; d > 0; d >>= 1) {
        s1 += __shfl_down(s1, d);
        s2 += __shfl_down(s2, d);
    }
    if (l == 0) { a1[i] = s1; a2[i] = s2; }
}

// ---------------- m1,m2 = max(a1),max(a2); E = exp(a - m); Sg = 0 ----------------
__global__ __launch_bounds__(1024) void k_max_exp(const float* __restrict__ a1,
        const float* __restrict__ a2, float* __restrict__ E1,
        float* __restrict__ E2, float* __restrict__ Sg) {
    __shared__ float red1[16], red2[16];
    const int t = threadIdx.x;
    float m1 = -1e30f, m2 = -1e30f;
    for (int i = t; i < NN; i += 1024) {
        m1 = fmaxf(m1, a1[i]);
        m2 = fmaxf(m2, a2[i]);
    }
    #pragma unroll
    for (int d = 32; d > 0; d >>= 1) {
        m1 = fmaxf(m1, __shfl_down(m1, d));
        m2 = fmaxf(m2, __shfl_down(m2, d));
    }
    if ((t & 63) == 0) { red1[t >> 6] = m1; red2[t >> 6] = m2; }
    __syncthreads();
    if (t == 0) {
        float mm1 = -1e30f, mm2 = -1e30f;
        for (int k = 0; k < 16; ++k) {
            mm1 = fmaxf(mm1, red1[k]);
            mm2 = fmaxf(mm2, red2[k]);
        }
        red1[0] = mm1; red2[0] = mm2;
        *Sg = 0.f;
    }
    __syncthreads();
    const float M1 = red1[0], M2 = red2[0];
    for (int i = t; i < NN; i += 1024) {
        E1[i] = expf(a1[i] - M1);
        E2[i] = expf(a2[i] - M2);
    }
}

// -------- w_raw[r] = E1[i_r]*E2[j_r] for the first 4096 row-major edges --------
__global__ __launch_bounds__(256) void k_edges(const int* __restrict__ adj,
        const float* __restrict__ E1, const float* __restrict__ E2,
        float* __restrict__ wraw) {
    __shared__ int scan[256];
    __shared__ int base_s;
    const int t = threadIdx.x;
    for (int i = t; i < NN; i += 256) wraw[i] = 0.f;
    if (t == 0) base_s = 0;
    __syncthreads();
    for (int row = 0; row < NN; ++row) {
        const int base = base_s;          // uniform
        if (base >= NN) break;            // uniform break
        const int* arow = adj + (size_t)row * NN;
        const int c0 = t * 16;
        int vals[16];
        int cnt = 0;
        #pragma unroll
        for (int j = 0; j < 16; ++j) { vals[j] = arow[c0 + j]; cnt += (vals[j] == 1); }
        scan[t] = cnt;
        __syncthreads();
        for (int d = 1; d < 256; d <<= 1) {
            const int y = (t >= d) ? scan[t - d] : 0;
            __syncthreads();
            scan[t] += y;
            __syncthreads();
        }
        const int total = scan[255];
        int r = base + scan[t] - cnt;     // exclusive prefix + base
        const float e1 = E1[row];
        #pragma unroll
        for (int j = 0; j < 16; ++j) {
            if (vals[j] == 1) {
                if (r < NN) wraw[r] = e1 * E2[c0 + j];
                ++r;
            }
        }
        __syncthreads();
        if (t == 0) base_s = base + total;
        __syncthreads();
    }
}

// -------- gt[f][j] = bf16(wraw[j] * h[j][f])  (transposed, K-contiguous) --------
__global__ __launch_bounds__(256) void k_g(const float* __restrict__ h,
        const float* __restrict__ wraw, uint16_t* __restrict__ gt) {
    __shared__ float tile[64][65];
    const int bj = blockIdx.x, bf = blockIdx.y;
    const int t = threadIdx.x;
    for (int e = t; e < 4096; e += 256) {
        const int r = e >> 6, c = e & 63;
        const int j = bj * 64 + r;
        tile[r][c] = h[(size_t)j * 256 + bf * 64 + c] * wraw[j];
    }
    __syncthreads();
    for (int e = t; e < 4096; e += 256) {
        const int r = e >> 6, c = e & 63;  // r: f-local, c: j-local
        gt[(size_t)(bf * 64 + r) * NN + bj * 64 + c] = f2bf(tile[c][r]);
    }
}

// -------- out_part = A @ G (bf16 MFMA, split-K) + S accumulation --------
// block: 256 thr (4 waves), tile BM=64 x BN=256, BK=64; wave = 64i x 64f
__global__ __launch_bounds__(256) void k_fused(const int* __restrict__ adj,
        const uint16_t* __restrict__ gt, const float* __restrict__ E1,
        const float* __restrict__ E2, float* __restrict__ part,
        float* __restrict__ Sg, int krange) {
    __shared__ __align__(16) uint16_t As[64 * 72];    // [i][k], pad 72
    __shared__ __align__(16) uint16_t Gs[256 * 72];   // [f][k], pad 72
    __shared__ float sred[4];
    const int ib = blockIdx.x, ks = blockIdx.y;
    const int t = threadIdx.x;
    const int wv = t >> 6, lane = t & 63;
    const int q = lane >> 4, m16 = lane & 15;
    const int i0 = ib * 64, k0 = ks * krange;
    const int ksteps = krange >> 6;

    fx4 acc[4][4];
    #pragma unroll
    for (int a = 0; a < 4; ++a)
        #pragma unroll
        for (int b = 0; b < 4; ++b) acc[a][b] = (fx4){0.f, 0.f, 0.f, 0.f};

    float e1r[4];
    #pragma unroll
    for (int p = 0; p < 4; ++p) e1r[p] = E1[i0 + p * 16 + (t >> 4)];

    float s_local = 0.f;

    for (int step = 0; step < ksteps; ++step) {
        const int kk = k0 + step * 64;
        // stage adj tile [64][64] -> bf16 {0,1}, fold S = sum(adj * E1[i]E2[k])
        const fx4 e2v = *(const fx4*)(E2 + kk + (t & 15) * 4);
        #pragma unroll
        for (int p = 0; p < 4; ++p) {
            const int r = p * 16 + (t >> 4);
            const int c = (t & 15) * 4;
            const int4 a = *(const int4*)(adj + (size_t)(i0 + r) * NN + kk + c);
            float sacc = 0.f;
            ushort4 bw;
            bw.x = (a.x == 1) ? 0x3F80 : 0; sacc += (a.x == 1) ? e2v[0] : 0.f;
            bw.y = (a.y == 1) ? 0x3F80 : 0; sacc += (a.y == 1) ? e2v[1] : 0.f;
            bw.z = (a.z == 1) ? 0x3F80 : 0; sacc += (a.z == 1) ? e2v[2] : 0.f;
            bw.w = (a.w == 1) ? 0x3F80 : 0; sacc += (a.w == 1) ? e2v[3] : 0.f;
            s_local += e1r[p] * sacc;
            *(ushort4*)(As + r * 72 + c) = bw;
        }
        // stage gt tile [256][64] (128B-contiguous global reads, L2-resident)
        #pragma unroll
        for (int p = 0; p < 8; ++p) {
            const int f = p * 32 + (t >> 3);
            const int ch = (t & 7) * 8;
            const s8v v = *(const s8v*)(gt + (size_t)f * NN + kk + ch);
            *(s8v*)(Gs + f * 72 + ch) = v;
        }
        __syncthreads();
        s8v afr[4][2];
        #pragma unroll
        for (int it = 0; it < 4; ++it)
            #pragma unroll
            for (int kh = 0; kh < 2; ++kh)
                afr[it][kh] = *(const s8v*)(As + (it * 16 + m16) * 72 + kh * 32 + q * 8);
        #pragma unroll
        for (int ft = 0; ft < 4; ++ft) {
            #pragma unroll
            for (int kh = 0; kh < 2; ++kh) {
                const s8v bfr = *(const s8v*)(Gs + (wv * 64 + ft * 16 + m16) * 72 + kh * 32 + q * 8);
                #pragma unroll
                for (int it = 0; it < 4; ++it)
                    acc[it][ft] = __builtin_amdgcn_mfma_f32_16x16x32_bf16(
                        afr[it][kh], bfr, acc[it][ft], 0, 0, 0);
            }
        }
        __syncthreads();
    }
    // block-reduce S, one atomic per block
    #pragma unroll
    for (int d = 32; d > 0; d >>= 1) s_local += __shfl_down(s_local, d);
    if (lane == 0) sred[wv] = s_local;
    __syncthreads();
    if (t == 0) atomicAdd(Sg, sred[0] + sred[1] + sred[2] + sred[3]);
    // store fp32 partials; C/D layout: col=lane&15, row=(lane>>4)*4+reg
    float* dst = part + (size_t)ks * NN * FDIM;
    #pragma unroll
    for (int it = 0; it < 4; ++it) {
        #pragma unroll
        for (int ft = 0; ft < 4; ++ft) {
            const int f = wv * 64 + ft * 16 + m16;
            #pragma unroll
            for (int r = 0; r < 4; ++r) {
                const int i = i0 + it * 16 + q * 4 + r;
                dst[(size_t)i * FDIM + f] = acc[it][ft][r];
            }
        }
    }
}

// -------- out = relu(sum_k part_k) / S --------
__global__ __launch_bounds__(256) void k_out(const float* __restrict__ part,
        const float* __restrict__ Sg, float* __restrict__ out, int nsplit) {
    const int idx = blockIdx.x * 256 + threadIdx.x;
    const float inv = 1.0f / (*Sg);
    fx4 s = {0.f, 0.f, 0.f, 0.f};
    for (int k = 0; k < nsplit; ++k)
        s += *(const fx4*)(part + (size_t)k * NN * FDIM + (size_t)idx * 4);
    fx4 r;
    r[0] = fmaxf(s[0], 0.f) * inv;
    r[1] = fmaxf(s[1], 0.f) * inv;
    r[2] = fmaxf(s[2], 0.f) * inv;
    r[3] = fmaxf(s[3], 0.f) * inv;
    *(fx4*)(out + (size_t)idx * 4) = r;
}

extern "C" void kernel_launch(void* const* d_in, const int* in_sizes, int n_in,
                              void* d_out, int out_size, void* d_ws, size_t ws_size,
                              hipStream_t stream) {
    const float* x     = (const float*)d_in[0];
    const int*   adj   = (const int*)d_in[1];
    const float* W     = (const float*)d_in[2];
    const float* bias  = (const float*)d_in[3];
    const float* att_w = (const float*)d_in[4];
    // att_b (d_in[5]) cancels exactly in the softmax — unused.
    float* out = (float*)d_out;
    char* ws = (char*)d_ws;
    float*    h    = (float*)(ws + 0);                    // 4 MB
    uint16_t* gt   = (uint16_t*)(ws + (size_t)4194304);   // 2 MB
    float*    a1   = (float*)(ws + 6291456);              // 16 KB
    float*    a2   = (float*)(ws + 6307840);              // 16 KB
    float*    E1   = (float*)(ws + 6324224);              // 16 KB
    float*    E2   = (float*)(ws + 6340608);              // 16 KB
    float*    wraw = (float*)(ws + 6356992);              // 16 KB
    float*    Sg   = (float*)(ws + 6373376);              // 256 B
    float*    part = (float*)(ws + 6373632);              // splitk * 4 MB

    const size_t avail = (ws_size > 6373632) ? (ws_size - 6373632) : 0;
    int splitk = 1;
    while (splitk < 8 &&
           (size_t)(splitk * 2) * NN * FDIM * sizeof(float) <= avail)
        splitk <<= 1;
    const int krange = NN / splitk;

    k_h      <<<dim3(64, 4), 256,  0, stream>>>(x, W, bias, h);
    k_a      <<<dim3(1024),  256,  0, stream>>>(h, att_w, a1, a2);
    k_max_exp<<<dim3(1),     1024, 0, stream>>>(a1, a2, E1, E2, Sg);
    k_edges  <<<dim3(1),     256,  0, stream>>>(adj, E1, E2, wraw);
    k_g      <<<dim3(64, 4), 256,  0, stream>>>(h, wraw, gt);
    k_fused  <<<dim3(64, splitk), 256, 0, stream>>>(adj, gt, E1, E2, part, Sg, krange);
    k_out    <<<dim3(1024),  256,  0, stream>>>(part, Sg, out, splitk);
}

// Round 2
// 173.467 us; speedup vs baseline: 1.0822x; 1.0822x over previous
//
#include <hip/hip_runtime.h>
#include <cstdint>
#include <cstddef>

#define NN 4096
#define FDIM 256

typedef __attribute__((ext_vector_type(4))) float fx4;
typedef __attribute__((ext_vector_type(2))) float fx2;
typedef __attribute__((ext_vector_type(8))) short s8v;

__device__ inline uint16_t f2bf(float f) {
    union { float f; uint32_t u; } v; v.f = f;
    uint32_t u = v.u;
    uint32_t r = (u + 0x7FFFu + ((u >> 16) & 1u)) >> 16;
    return (uint16_t)r;
}

// ---------------- h = x @ W.T + b  (fp32, 32x64 tiles, 2x4 micro) ----------------
// grid(128,4) = 512 blocks -> 2 blocks/CU (vs 1 before); 26 KB LDS.
__global__ __launch_bounds__(256) void k_h(const float* __restrict__ x,
        const float* __restrict__ W, const float* __restrict__ bias,
        float* __restrict__ h) {
    __shared__ __align__(16) float xs[64 * 34];  // [k][i], pad 34 (no swizzle: 2-way free)
    __shared__ __align__(16) float wt[64 * 68];  // [k][f], swizzled (breaks 8-way write conflict)
    const int bi = blockIdx.x, bf = blockIdx.y;
    const int t = threadIdx.x;
    const int tx = t & 15, ty = t >> 4;          // tx: f-group (4 cols), ty: i-group (2 rows)
    float acc[2][4] = {};
    for (int k0 = 0; k0 < 256; k0 += 64) {
        for (int e = t; e < 2048; e += 256) {
            const int c = e & 63, r = e >> 6;    // c: k, r: i
            xs[c * 34 + r] = x[(size_t)(bi * 32 + r) * 256 + k0 + c];
        }
        for (int e = t; e < 4096; e += 256) {
            const int c = e & 63, r = e >> 6;    // c: k, r: f
            const int sw = 8 * ((c & 7) ^ ((c >> 3) & 7));
            wt[c * 68 + (r ^ sw)] = W[(size_t)(bf * 64 + r) * 256 + k0 + c];
        }
        __syncthreads();
        #pragma unroll 16
        for (int k = 0; k < 64; ++k) {
            const int sw = 8 * ((k & 7) ^ ((k >> 3) & 7));
            const fx2 av = *(const fx2*)(xs + k * 34 + ty * 2);
            const fx4 bv = *(const fx4*)(wt + k * 68 + ((tx * 4) ^ sw));
            #pragma unroll
            for (int u = 0; u < 2; ++u)
                #pragma unroll
                for (int v = 0; v < 4; ++v)
                    acc[u][v] += av[u] * bv[v];
        }
        __syncthreads();
    }
    const fx4 bv = *(const fx4*)(bias + bf * 64 + tx * 4);
    #pragma unroll
    for (int u = 0; u < 2; ++u) {
        const int i = bi * 32 + ty * 2 + u;
        fx4 r;
        #pragma unroll
        for (int v = 0; v < 4; ++v) r[v] = acc[u][v] + bv[v];
        *(fx4*)(h + (size_t)i * 256 + bf * 64 + tx * 4) = r;
    }
}

// ---------------- a1 = h @ w1, a2 = h @ w2 ----------------
__global__ __launch_bounds__(256) void k_a(const float* __restrict__ h,
        const float* __restrict__ att_w, float* __restrict__ a1,
        float* __restrict__ a2) {
    const int wv = threadIdx.x >> 6, l = threadIdx.x & 63;
    const int i = blockIdx.x * 4 + wv;
    float s1 = 0.f, s2 = 0.f;
    #pragma unroll
    for (int c = l; c < 256; c += 64) {
        const float hv = h[(size_t)i * 256 + c];
        s1 += hv * att_w[c];
        s2 += hv * att_w[256 + c];
    }
    #pragma unroll
    for (int d = 32; d > 0; d >>= 1) {
        s1 += __shfl_down(s1, d);
        s2 += __shfl_down(s2, d);
    }
    if (l == 0) { a1[i] = s1; a2[i] = s2; }
}

// ---------------- m1,m2 = max(a1),max(a2); E = exp(a - m); Sg = 0 ----------------
__global__ __launch_bounds__(1024) void k_max_exp(const float* __restrict__ a1,
        const float* __restrict__ a2, float* __restrict__ E1,
        float* __restrict__ E2, float* __restrict__ Sg) {
    __shared__ float red1[16], red2[16];
    const int t = threadIdx.x;
    float m1 = -1e30f, m2 = -1e30f;
    for (int i = t; i < NN; i += 1024) {
        m1 = fmaxf(m1, a1[i]);
        m2 = fmaxf(m2, a2[i]);
    }
    #pragma unroll
    for (int d = 32; d > 0; d >>= 1) {
        m1 = fmaxf(m1, __shfl_down(m1, d));
        m2 = fmaxf(m2, __shfl_down(m2, d));
    }
    if ((t & 63) == 0) { red1[t >> 6] = m1; red2[t >> 6] = m2; }
    __syncthreads();
    if (t == 0) {
        float mm1 = -1e30f, mm2 = -1e30f;
        for (int k = 0; k < 16; ++k) {
            mm1 = fmaxf(mm1, red1[k]);
            mm2 = fmaxf(mm2, red2[k]);
        }
        red1[0] = mm1; red2[0] = mm2;
        *Sg = 0.f;
    }
    __syncthreads();
    const float M1 = red1[0], M2 = red2[0];
    for (int i = t; i < NN; i += 1024) {
        E1[i] = expf(a1[i] - M1);
        E2[i] = expf(a2[i] - M2);
    }
}

// -------- w_raw[r] = E1[i_r]*E2[j_r] for the first 4096 row-major edges --------
// int4 vector loads + shfl wave-scan + tiny LDS cross-wave scan; 2 barriers/row.
__global__ __launch_bounds__(256) void k_edges(const int* __restrict__ adj,
        const float* __restrict__ E1, const float* __restrict__ E2,
        float* __restrict__ wraw) {
    __shared__ int wtot[4];
    __shared__ int base_s;
    const int t = threadIdx.x, lane = t & 63, wv = t >> 6;
    for (int i = t; i < NN; i += 256) wraw[i] = 0.f;
    if (t == 0) base_s = 0;
    __syncthreads();
    for (int row = 0; row < NN; ++row) {
        const int base = base_s;          // uniform
        if (base >= NN) break;            // uniform break
        const int* arow = adj + (size_t)row * NN + t * 16;
        int4 a0 = ((const int4*)arow)[0];
        int4 a1v = ((const int4*)arow)[1];
        int4 a2v = ((const int4*)arow)[2];
        int4 a3v = ((const int4*)arow)[3];
        int v[16] = {a0.x, a0.y, a0.z, a0.w, a1v.x, a1v.y, a1v.z, a1v.w,
                     a2v.x, a2v.y, a2v.z, a2v.w, a3v.x, a3v.y, a3v.z, a3v.w};
        int cnt = 0;
        #pragma unroll
        for (int j = 0; j < 16; ++j) cnt += (v[j] == 1);
        // inclusive wave scan
        int inc = cnt;
        #pragma unroll
        for (int d = 1; d < 64; d <<= 1) {
            const int y = __shfl_up(inc, d);
            if (lane >= d) inc += y;
        }
        if (lane == 63) wtot[wv] = inc;
        __syncthreads();                  // B1: wtot visible
        int wbase = 0;
        #pragma unroll
        for (int w = 0; w < 4; ++w) wbase += (w < wv) ? wtot[w] : 0;
        const int total = wtot[0] + wtot[1] + wtot[2] + wtot[3];
        if (t == 0) base_s = base + total;
        int r = base + wbase + inc - cnt; // exclusive global rank
        if (cnt && r < NN) {
            const float e1 = E1[row];
            #pragma unroll
            for (int j = 0; j < 16; ++j) {
                if (v[j] == 1) {
                    if (r < NN) wraw[r] = e1 * E2[t * 16 + j];
                    ++r;
                }
            }
        }
        __syncthreads();                  // B2: base_s/wtot safe for next iter
    }
}

// -------- gt[f][j] = bf16(wraw[j] * h[j][f])  (transposed, K-contiguous) --------
__global__ __launch_bounds__(256) void k_g(const float* __restrict__ h,
        const float* __restrict__ wraw, uint16_t* __restrict__ gt) {
    __shared__ float tile[64][65];
    const int bj = blockIdx.x, bf = blockIdx.y;
    const int t = threadIdx.x;
    for (int e = t; e < 4096; e += 256) {
        const int r = e >> 6, c = e & 63;
        const int j = bj * 64 + r;
        tile[r][c] = h[(size_t)j * 256 + bf * 64 + c] * wraw[j];
    }
    __syncthreads();
    for (int e = t; e < 4096; e += 256) {
        const int r = e >> 6, c = e & 63;  // r: f-local, c: j-local
        gt[(size_t)(bf * 64 + r) * NN + bj * 64 + c] = f2bf(tile[c][r]);
    }
}

// -------- out_part = A @ G (bf16 MFMA, split-K) + S accumulation --------
// block: 256 thr (4 waves), tile BM=64 x BN=256, BK=64; wave = 64i x 64f
__global__ __launch_bounds__(256) void k_fused(const int* __restrict__ adj,
        const uint16_t* __restrict__ gt, const float* __restrict__ E1,
        const float* __restrict__ E2, float* __restrict__ part,
        float* __restrict__ Sg, int krange) {
    __shared__ __align__(16) uint16_t As[64 * 72];    // [i][k], pad 72
    __shared__ __align__(16) uint16_t Gs[256 * 72];   // [f][k], pad 72
    __shared__ float sred[4];
    const int ib = blockIdx.x, ks = blockIdx.y;
    const int t = threadIdx.x;
    const int wv = t >> 6, lane = t & 63;
    const int q = lane >> 4, m16 = lane & 15;
    const int i0 = ib * 64, k0 = ks * krange;
    const int ksteps = krange >> 6;

    fx4 acc[4][4];
    #pragma unroll
    for (int a = 0; a < 4; ++a)
        #pragma unroll
        for (int b = 0; b < 4; ++b) acc[a][b] = (fx4){0.f, 0.f, 0.f, 0.f};

    float e1r[4];
    #pragma unroll
    for (int p = 0; p < 4; ++p) e1r[p] = E1[i0 + p * 16 + (t >> 4)];

    float s_local = 0.f;

    for (int step = 0; step < ksteps; ++step) {
        const int kk = k0 + step * 64;
        // stage adj tile [64][64] -> bf16 {0,1}, fold S = sum(adj * E1[i]E2[k])
        const fx4 e2v = *(const fx4*)(E2 + kk + (t & 15) * 4);
        #pragma unroll
        for (int p = 0; p < 4; ++p) {
            const int r = p * 16 + (t >> 4);
            const int c = (t & 15) * 4;
            const int4 a = *(const int4*)(adj + (size_t)(i0 + r) * NN + kk + c);
            float sacc = 0.f;
            ushort4 bw;
            bw.x = (a.x == 1) ? 0x3F80 : 0; sacc += (a.x == 1) ? e2v[0] : 0.f;
            bw.y = (a.y == 1) ? 0x3F80 : 0; sacc += (a.y == 1) ? e2v[1] : 0.f;
            bw.z = (a.z == 1) ? 0x3F80 : 0; sacc += (a.z == 1) ? e2v[2] : 0.f;
            bw.w = (a.w == 1) ? 0x3F80 : 0; sacc += (a.w == 1) ? e2v[3] : 0.f;
            s_local += e1r[p] * sacc;
            *(ushort4*)(As + r * 72 + c) = bw;
        }
        // stage gt tile [256][64] (128B-contiguous global reads, L2-resident)
        #pragma unroll
        for (int p = 0; p < 8; ++p) {
            const int f = p * 32 + (t >> 3);
            const int ch = (t & 7) * 8;
            const s8v v = *(const s8v*)(gt + (size_t)f * NN + kk + ch);
            *(s8v*)(Gs + f * 72 + ch) = v;
        }
        __syncthreads();
        s8v afr[4][2];
        #pragma unroll
        for (int it = 0; it < 4; ++it)
            #pragma unroll
            for (int kh = 0; kh < 2; ++kh)
                afr[it][kh] = *(const s8v*)(As + (it * 16 + m16) * 72 + kh * 32 + q * 8);
        #pragma unroll
        for (int ft = 0; ft < 4; ++ft) {
            #pragma unroll
            for (int kh = 0; kh < 2; ++kh) {
                const s8v bfr = *(const s8v*)(Gs + (wv * 64 + ft * 16 + m16) * 72 + kh * 32 + q * 8);
                #pragma unroll
                for (int it = 0; it < 4; ++it)
                    acc[it][ft] = __builtin_amdgcn_mfma_f32_16x16x32_bf16(
                        afr[it][kh], bfr, acc[it][ft], 0, 0, 0);
            }
        }
        __syncthreads();
    }
    // block-reduce S, one atomic per block
    #pragma unroll
    for (int d = 32; d > 0; d >>= 1) s_local += __shfl_down(s_local, d);
    if (lane == 0) sred[wv] = s_local;
    __syncthreads();
    if (t == 0) atomicAdd(Sg, sred[0] + sred[1] + sred[2] + sred[3]);
    // store fp32 partials; C/D layout: col=lane&15, row=(lane>>4)*4+reg
    float* dst = part + (size_t)ks * NN * FDIM;
    #pragma unroll
    for (int it = 0; it < 4; ++it) {
        #pragma unroll
        for (int ft = 0; ft < 4; ++ft) {
            const int f = wv * 64 + ft * 16 + m16;
            #pragma unroll
            for (int r = 0; r < 4; ++r) {
                const int i = i0 + it * 16 + q * 4 + r;
                dst[(size_t)i * FDIM + f] = acc[it][ft][r];
            }
        }
    }
}

// -------- out = relu(sum_k part_k) / S --------
__global__ __launch_bounds__(256) void k_out(const float* __restrict__ part,
        const float* __restrict__ Sg, float* __restrict__ out, int nsplit) {
    const int idx = blockIdx.x * 256 + threadIdx.x;
    const float inv = 1.0f / (*Sg);
    fx4 s = {0.f, 0.f, 0.f, 0.f};
    for (int k = 0; k < nsplit; ++k)
        s += *(const fx4*)(part + (size_t)k * NN * FDIM + (size_t)idx * 4);
    fx4 r;
    r[0] = fmaxf(s[0], 0.f) * inv;
    r[1] = fmaxf(s[1], 0.f) * inv;
    r[2] = fmaxf(s[2], 0.f) * inv;
    r[3] = fmaxf(s[3], 0.f) * inv;
    *(fx4*)(out + (size_t)idx * 4) = r;
}

extern "C" void kernel_launch(void* const* d_in, const int* in_sizes, int n_in,
                              void* d_out, int out_size, void* d_ws, size_t ws_size,
                              hipStream_t stream) {
    const float* x     = (const float*)d_in[0];
    const int*   adj   = (const int*)d_in[1];
    const float* W     = (const float*)d_in[2];
    const float* bias  = (const float*)d_in[3];
    const float* att_w = (const float*)d_in[4];
    // att_b (d_in[5]) cancels exactly in the softmax — unused.
    float* out = (float*)d_out;
    char* ws = (char*)d_ws;
    float*    h    = (float*)(ws + 0);                    // 4 MB
    uint16_t* gt   = (uint16_t*)(ws + (size_t)4194304);   // 2 MB
    float*    a1   = (float*)(ws + 6291456);              // 16 KB
    float*    a2   = (float*)(ws + 6307840);              // 16 KB
    float*    E1   = (float*)(ws + 6324224);              // 16 KB
    float*    E2   = (float*)(ws + 6340608);              // 16 KB
    float*    wraw = (float*)(ws + 6356992);              // 16 KB
    float*    Sg   = (float*)(ws + 6373376);              // 256 B
    float*    part = (float*)(ws + 6373632);              // splitk * 4 MB

    const size_t avail = (ws_size > 6373632) ? (ws_size - 6373632) : 0;
    int splitk = 1;
    while (splitk < 8 &&
           (size_t)(splitk * 2) * NN * FDIM * sizeof(float) <= avail)
        splitk <<= 1;
    const int krange = NN / splitk;

    k_h      <<<dim3(128, 4), 256, 0, stream>>>(x, W, bias, h);
    k_a      <<<dim3(1024),  256,  0, stream>>>(h, att_w, a1, a2);
    k_max_exp<<<dim3(1),     1024, 0, stream>>>(a1, a2, E1, E2, Sg);
    k_edges  <<<dim3(1),     256,  0, stream>>>(adj, E1, E2, wraw);
    k_g      <<<dim3(64, 4), 256,  0, stream>>>(h, wraw, gt);
    k_fused  <<<dim3(64, splitk), 256, 0, stream>>>(adj, gt, E1, E2, part, Sg, krange);
    k_out    <<<dim3(1024),  256,  0, stream>>>(part, Sg, out, splitk);
}

// Round 3
// 159.515 us; speedup vs baseline: 1.1769x; 1.0875x over previous
//
#include <hip/hip_runtime.h>
#include <cstdint>
#include <cstddef>

#define NN 4096
#define FDIM 256

typedef __attribute__((ext_vector_type(4))) float fx4;
typedef __attribute__((ext_vector_type(2))) float fx2;
typedef __attribute__((ext_vector_type(8))) short s8v;

__device__ inline uint16_t f2bf(float f) {
    union { float f; uint32_t u; } v; v.f = f;
    uint32_t u = v.u;
    uint32_t r = (u + 0x7FFFu + ((u >> 16) & 1u)) >> 16;
    return (uint16_t)r;
}

// ---------------- h = x @ W.T + b  (fp32, 32x64 tiles, 2x4 micro) ----------------
// Double-buffered LDS + register prefetch: phase p+1 global loads overlap phase p
// compute; one barrier per phase. grid(128,4)=512 blocks -> 2 blocks/CU, 52KB LDS.
__global__ __launch_bounds__(256) void k_h(const float* __restrict__ x,
        const float* __restrict__ W, const float* __restrict__ bias,
        float* __restrict__ h) {
    __shared__ __align__(16) float xs[2][64 * 34];  // [k][i]
    __shared__ __align__(16) float wt[2][64 * 68];  // [k][f] swizzled
    const int bi = blockIdx.x, bf = blockIdx.y;
    const int t = threadIdx.x;
    const int tx = t & 15, ty = t >> 4;
    float acc[2][4] = {};
    float rx[8], rw[16];
    #pragma unroll
    for (int u = 0; u < 8; ++u) {
        const int e = t + 256 * u, r = e >> 6, c = e & 63;
        rx[u] = x[(size_t)(bi * 32 + r) * 256 + c];
    }
    #pragma unroll
    for (int u = 0; u < 16; ++u) {
        const int e = t + 256 * u, r = e >> 6, c = e & 63;
        rw[u] = W[(size_t)(bf * 64 + r) * 256 + c];
    }
    for (int p = 0; p < 4; ++p) {
        float* xb = xs[p & 1];
        float* wb = wt[p & 1];
        #pragma unroll
        for (int u = 0; u < 8; ++u) {
            const int e = t + 256 * u, r = e >> 6, c = e & 63;
            xb[c * 34 + r] = rx[u];
        }
        #pragma unroll
        for (int u = 0; u < 16; ++u) {
            const int e = t + 256 * u, r = e >> 6, c = e & 63;
            const int sw = 8 * ((c & 7) ^ ((c >> 3) & 7));
            wb[c * 68 + (r ^ sw)] = rw[u];
        }
        __syncthreads();
        if (p < 3) {
            const int k0 = (p + 1) * 64;
            #pragma unroll
            for (int u = 0; u < 8; ++u) {
                const int e = t + 256 * u, r = e >> 6, c = e & 63;
                rx[u] = x[(size_t)(bi * 32 + r) * 256 + k0 + c];
            }
            #pragma unroll
            for (int u = 0; u < 16; ++u) {
                const int e = t + 256 * u, r = e >> 6, c = e & 63;
                rw[u] = W[(size_t)(bf * 64 + r) * 256 + k0 + c];
            }
        }
        #pragma unroll 16
        for (int k = 0; k < 64; ++k) {
            const int sw = 8 * ((k & 7) ^ ((k >> 3) & 7));
            const fx2 av = *(const fx2*)(xb + k * 34 + ty * 2);
            const fx4 bv = *(const fx4*)(wb + k * 68 + ((tx * 4) ^ sw));
            #pragma unroll
            for (int u = 0; u < 2; ++u)
                #pragma unroll
                for (int v = 0; v < 4; ++v)
                    acc[u][v] += av[u] * bv[v];
        }
        // no trailing barrier: double buffer makes next store safe
    }
    const fx4 bv = *(const fx4*)(bias + bf * 64 + tx * 4);
    #pragma unroll
    for (int u = 0; u < 2; ++u) {
        const int i = bi * 32 + ty * 2 + u;
        fx4 r;
        #pragma unroll
        for (int v = 0; v < 4; ++v) r[v] = acc[u][v] + bv[v];
        *(fx4*)(h + (size_t)i * 256 + bf * 64 + tx * 4) = r;
    }
}

// ---------------- a1 = h @ w1, a2 = h @ w2 ----------------
__global__ __launch_bounds__(256) void k_a(const float* __restrict__ h,
        const float* __restrict__ att_w, float* __restrict__ a1,
        float* __restrict__ a2) {
    const int wv = threadIdx.x >> 6, l = threadIdx.x & 63;
    const int i = blockIdx.x * 4 + wv;
    float s1 = 0.f, s2 = 0.f;
    #pragma unroll
    for (int c = l; c < 256; c += 64) {
        const float hv = h[(size_t)i * 256 + c];
        s1 += hv * att_w[c];
        s2 += hv * att_w[256 + c];
    }
    #pragma unroll
    for (int d = 32; d > 0; d >>= 1) {
        s1 += __shfl_down(s1, d);
        s2 += __shfl_down(s2, d);
    }
    if (l == 0) { a1[i] = s1; a2[i] = s2; }
}

// ---- k_prep: max/exp (E1,E2) + Sg=0 + first-4096-edge scan, one block ----
__global__ __launch_bounds__(1024) void k_prep(const float* __restrict__ a1,
        const float* __restrict__ a2, const int* __restrict__ adj,
        float* __restrict__ E1, float* __restrict__ E2,
        float* __restrict__ wraw, float* __restrict__ Sg) {
    __shared__ float E1s[NN];
    __shared__ float E2s[NN];
    __shared__ float red1[16], red2[16];
    __shared__ int wtot[16];
    __shared__ int base_s;
    const int t = threadIdx.x, lane = t & 63, wv = t >> 6;
    const fx4 v1 = *(const fx4*)(a1 + t * 4);
    const fx4 v2 = *(const fx4*)(a2 + t * 4);
    float m1 = fmaxf(fmaxf(v1[0], v1[1]), fmaxf(v1[2], v1[3]));
    float m2 = fmaxf(fmaxf(v2[0], v2[1]), fmaxf(v2[2], v2[3]));
    #pragma unroll
    for (int d = 32; d > 0; d >>= 1) {
        m1 = fmaxf(m1, __shfl_down(m1, d));
        m2 = fmaxf(m2, __shfl_down(m2, d));
    }
    if (lane == 0) { red1[wv] = m1; red2[wv] = m2; }
    __syncthreads();
    if (t == 0) {
        float mm1 = -1e30f, mm2 = -1e30f;
        for (int k = 0; k < 16; ++k) {
            mm1 = fmaxf(mm1, red1[k]);
            mm2 = fmaxf(mm2, red2[k]);
        }
        red1[0] = mm1; red2[0] = mm2;
        *Sg = 0.f;
        base_s = 0;
    }
    __syncthreads();
    const float M1 = red1[0], M2 = red2[0];
    fx4 e1v, e2v, z4 = {0.f, 0.f, 0.f, 0.f};
    #pragma unroll
    for (int j = 0; j < 4; ++j) {
        e1v[j] = expf(v1[j] - M1);
        e2v[j] = expf(v2[j] - M2);
    }
    *(fx4*)(E1s + t * 4) = e1v;
    *(fx4*)(E2s + t * 4) = e2v;
    *(fx4*)(E1 + t * 4) = e1v;
    *(fx4*)(E2 + t * 4) = e2v;
    *(fx4*)(wraw + t * 4) = z4;
    __syncthreads();
    for (int row = 0; row < NN; ++row) {
        const int base = base_s;           // uniform
        if (base >= NN) break;             // uniform break
        const int4 a = ((const int4*)(adj + (size_t)row * NN))[t];
        const int vj[4] = {a.x, a.y, a.z, a.w};
        int cnt = 0;
        #pragma unroll
        for (int j = 0; j < 4; ++j) cnt += (vj[j] == 1);
        int inc = cnt;
        #pragma unroll
        for (int d = 1; d < 64; d <<= 1) {
            const int y = __shfl_up(inc, d);
            if (lane >= d) inc += y;
        }
        if (lane == 63) wtot[wv] = inc;
        __syncthreads();                   // B1
        int wbase = 0, total = 0;
        #pragma unroll
        for (int w = 0; w < 16; ++w) {
            const int xw = wtot[w];
            total += xw;
            wbase += (w < wv) ? xw : 0;
        }
        if (t == 0) base_s = base + total;
        int r = base + wbase + inc - cnt;
        if (cnt && r < NN) {
            const float e1 = E1s[row];
            #pragma unroll
            for (int j = 0; j < 4; ++j) {
                if (vj[j] == 1) {
                    if (r < NN) wraw[r] = e1 * E2s[t * 4 + j];
                    ++r;
                }
            }
        }
        __syncthreads();                   // B2
    }
}

// -------- gt[f][j] = bf16(wraw[j] * h[j][f])  (transposed, K-contiguous) --------
__global__ __launch_bounds__(256) void k_g(const float* __restrict__ h,
        const float* __restrict__ wraw, uint16_t* __restrict__ gt) {
    __shared__ float tile[64][65];
    const int bj = blockIdx.x, bf = blockIdx.y;
    const int t = threadIdx.x;
    for (int e = t; e < 4096; e += 256) {
        const int r = e >> 6, c = e & 63;
        const int j = bj * 64 + r;
        tile[r][c] = h[(size_t)j * 256 + bf * 64 + c] * wraw[j];
    }
    __syncthreads();
    for (int e = t; e < 4096; e += 256) {
        const int r = e >> 6, c = e & 63;  // r: f-local, c: j-local
        gt[(size_t)(bf * 64 + r) * NN + bj * 64 + c] = f2bf(tile[c][r]);
    }
}

// -------- out_part = A @ G (bf16 MFMA, split-K); S via appended E2 column --------
// block: 256 thr (4 waves), tile BM=64 x BN=256, BK=64; wave = 64i x 64f.
// Gs rows 0..255 = gt; row 256 = E2 (bf16); rows 257..271 = 0. Wave 3 computes the
// extra 16-col tile -> C[i][256] = adj_row . E2; epilogue: S += E1[i]*C[i][256].
__global__ __launch_bounds__(256) void k_fused(const int* __restrict__ adj,
        const uint16_t* __restrict__ gt, const float* __restrict__ E1,
        const float* __restrict__ E2, float* __restrict__ part,
        float* __restrict__ Sg, int krange) {
    __shared__ __align__(16) uint16_t As[64 * 72];
    __shared__ __align__(16) uint16_t Gs[272 * 72];
    const int ib = blockIdx.x, ks = blockIdx.y;
    const int t = threadIdx.x;
    const int wv = t >> 6, lane = t & 63;
    const int q = lane >> 4, m16 = lane & 15;
    const int i0 = ib * 64, k0 = ks * krange;
    const int ksteps = krange >> 6;

    fx4 acc[4][4];
    #pragma unroll
    for (int a = 0; a < 4; ++a)
        #pragma unroll
        for (int b = 0; b < 4; ++b) acc[a][b] = (fx4){0.f, 0.f, 0.f, 0.f};
    fx4 accS[4];
    #pragma unroll
    for (int a = 0; a < 4; ++a) accS[a] = (fx4){0.f, 0.f, 0.f, 0.f};

    // zero rows 257..271 once (covered by first in-loop barrier)
    for (int e = t; e < 15 * 72; e += 256) Gs[257 * 72 + e] = 0;

    for (int step = 0; step < ksteps; ++step) {
        const int kk = k0 + step * 64;
        // ---- As: adj -> bf16 {0,1} via bit-trick (adj values are 0/1) ----
        #pragma unroll
        for (int p = 0; p < 4; ++p) {
            const int r = p * 16 + (t >> 4);
            const int c4 = (t & 15) * 4;
            const int4 a = *(const int4*)(adj + (size_t)(i0 + r) * NN + kk + c4);
            uint2 w;
            w.x = (uint32_t)(a.x | (a.y << 16)) * 0x3F80u;
            w.y = (uint32_t)(a.z | (a.w << 16)) * 0x3F80u;
            *(uint2*)(&As[r * 72 + c4]) = w;
        }
        // ---- Gs main: gt tile [256][64] ----
        #pragma unroll
        for (int p = 0; p < 8; ++p) {
            const int f = p * 32 + (t >> 3);
            const int ch = (t & 7) * 8;
            const s8v v = *(const s8v*)(gt + (size_t)f * NN + kk + ch);
            *(s8v*)(Gs + f * 72 + ch) = v;
        }
        // ---- Gs row 256: E2 chunk in bf16 ----
        if (t < 8) {
            const float* e2p = E2 + kk + t * 8;
            uint32_t* dst = (uint32_t*)(&Gs[256 * 72 + t * 8]);
            #pragma unroll
            for (int j = 0; j < 4; ++j)
                dst[j] = (uint32_t)f2bf(e2p[2 * j]) |
                         ((uint32_t)f2bf(e2p[2 * j + 1]) << 16);
        }
        __syncthreads();
        s8v afr[4][2];
        #pragma unroll
        for (int it = 0; it < 4; ++it)
            #pragma unroll
            for (int kh = 0; kh < 2; ++kh)
                afr[it][kh] = *(const s8v*)(As + (it * 16 + m16) * 72 + kh * 32 + q * 8);
        #pragma unroll
        for (int ft = 0; ft < 4; ++ft) {
            #pragma unroll
            for (int kh = 0; kh < 2; ++kh) {
                const s8v bfr = *(const s8v*)(Gs + (wv * 64 + ft * 16 + m16) * 72 + kh * 32 + q * 8);
                #pragma unroll
                for (int it = 0; it < 4; ++it)
                    acc[it][ft] = __builtin_amdgcn_mfma_f32_16x16x32_bf16(
                        afr[it][kh], bfr, acc[it][ft], 0, 0, 0);
            }
        }
        if (wv == 3) {  // wave-uniform: S-column tile
            #pragma unroll
            for (int kh = 0; kh < 2; ++kh) {
                const s8v bfrS = *(const s8v*)(Gs + (256 + m16) * 72 + kh * 32 + q * 8);
                #pragma unroll
                for (int it = 0; it < 4; ++it)
                    accS[it] = __builtin_amdgcn_mfma_f32_16x16x32_bf16(
                        afr[it][kh], bfrS, accS[it], 0, 0, 0);
            }
        }
        __syncthreads();
    }
    // ---- S epilogue (wave 3; lanes m16>0 hold zeros from zero-rows) ----
    if (wv == 3) {
        float s_local = 0.f;
        #pragma unroll
        for (int it = 0; it < 4; ++it)
            #pragma unroll
            for (int r = 0; r < 4; ++r)
                s_local += accS[it][r] * E1[i0 + it * 16 + q * 4 + r];
        #pragma unroll
        for (int d = 32; d > 0; d >>= 1) s_local += __shfl_down(s_local, d);
        if (lane == 0) atomicAdd(Sg, s_local);
    }
    // ---- C partials; C/D layout: col=lane&15, row=(lane>>4)*4+reg ----
    float* dst = part + (size_t)ks * NN * FDIM;
    #pragma unroll
    for (int it = 0; it < 4; ++it) {
        #pragma unroll
        for (int ft = 0; ft < 4; ++ft) {
            const int f = wv * 64 + ft * 16 + m16;
            #pragma unroll
            for (int r = 0; r < 4; ++r) {
                const int i = i0 + it * 16 + q * 4 + r;
                dst[(size_t)i * FDIM + f] = acc[it][ft][r];
            }
        }
    }
}

// -------- out = relu(sum_k part_k) / S  (XCD-aligned with k_fused writers) --------
__global__ __launch_bounds__(256) void k_out(const float* __restrict__ part,
        const float* __restrict__ Sg, float* __restrict__ out, int nsplit) {
    const int b = blockIdx.x;
    const int ib = (b & 7) + 8 * ((b >> 3) & 7);   // XCD(b)=b%8 == ib%8
    const int sub = b >> 6;
    const int t = threadIdx.x;
    const int row = ib * 64 + sub * 4 + (t >> 6);
    const size_t idx = (size_t)row * 256 + (t & 63) * 4;
    const float inv = 1.0f / (*Sg);
    fx4 s = {0.f, 0.f, 0.f, 0.f};
    for (int k = 0; k < nsplit; ++k)
        s += *(const fx4*)(part + (size_t)k * NN * FDIM + idx);
    fx4 r;
    r[0] = fmaxf(s[0], 0.f) * inv;
    r[1] = fmaxf(s[1], 0.f) * inv;
    r[2] = fmaxf(s[2], 0.f) * inv;
    r[3] = fmaxf(s[3], 0.f) * inv;
    *(fx4*)(out + idx) = r;
}

extern "C" void kernel_launch(void* const* d_in, const int* in_sizes, int n_in,
                              void* d_out, int out_size, void* d_ws, size_t ws_size,
                              hipStream_t stream) {
    const float* x     = (const float*)d_in[0];
    const int*   adj   = (const int*)d_in[1];
    const float* W     = (const float*)d_in[2];
    const float* bias  = (const float*)d_in[3];
    const float* att_w = (const float*)d_in[4];
    // att_b (d_in[5]) cancels exactly in the softmax — unused.
    float* out = (float*)d_out;
    char* ws = (char*)d_ws;
    float*    h    = (float*)(ws + 0);                    // 4 MB
    uint16_t* gt   = (uint16_t*)(ws + (size_t)4194304);   // 2 MB
    float*    a1   = (float*)(ws + 6291456);              // 16 KB
    float*    a2   = (float*)(ws + 6307840);              // 16 KB
    float*    E1   = (float*)(ws + 6324224);              // 16 KB
    float*    E2   = (float*)(ws + 6340608);              // 16 KB
    float*    wraw = (float*)(ws + 6356992);              // 16 KB
    float*    Sg   = (float*)(ws + 6373376);              // 256 B
    float*    part = (float*)(ws + 6373632);              // splitk * 4 MB

    const size_t avail = (ws_size > 6373632) ? (ws_size - 6373632) : 0;
    int splitk = 1;
    while (splitk < 8 &&
           (size_t)(splitk * 2) * NN * FDIM * sizeof(float) <= avail)
        splitk <<= 1;
    const int krange = NN / splitk;

    k_h   <<<dim3(128, 4), 256, 0, stream>>>(x, W, bias, h);
    k_a   <<<dim3(1024), 256, 0, stream>>>(h, att_w, a1, a2);
    k_prep<<<dim3(1), 1024, 0, stream>>>(a1, a2, adj, E1, E2, wraw, Sg);
    k_g   <<<dim3(64, 4), 256, 0, stream>>>(h, wraw, gt);
    k_fused<<<dim3(64, splitk), 256, 0, stream>>>(adj, gt, E1, E2, part, Sg, krange);
    k_out <<<dim3(1024), 256, 0, stream>>>(part, Sg, out, splitk);
}